// Round 1
// baseline (447.409 us; speedup 1.0000x reference)
//
#include <hip/hip_runtime.h>
#include <hip/hip_bf16.h>

// GroupNLMSMemory: B=512, D=256, M=100000
// out = [retrieved 512x256 | attn 512x100000] (f32)
// Plan (recompute-flash):
//   k0 : x row norms -> ws (10/xn), zero retrieved region
//   k0b: V (f32 [M][256]) -> ws VT bf16 [256][MP], MP=100032 (zero-padded tail)
//   k1 : QK^T (bf16 MFMA) + per-lane online softmax stats per (chunk, m-half)
//        -> PSTAT in tail of attn region
//   k2 : merge PSTAT -> m_final, 1/l in ws
//   k3 : recompute QK^T, write normalized attn, PV-accumulate (bf16 MFMA)
//        -> per-chunk partial retrieved in ws (or atomicAdd fallback)
//   k4 : reduce partials -> retrieved

#define MCOLS 100000
#define MP    100032              // padded VT column count (mult of 64)
#define DDIM  256
#define CHUNK 832                 // 13 tiles of 64
#define NTFULL 13
#define NCHUNK 121                // ceil(100000/832); last chunk = 160 cols
#define NSTAT  242                // NCHUNK * 2 m-halves
#define PSTAT_OFF 51083264       // 131072 + 512*100000 - 242*512*2
#define WS_RXN  0
#define WS_MFIN 512
#define WS_RCPL 1024
#define WS_VT_BYTE   65536ull
#define WS_VT_END    (65536ull + 2ull*DDIM*MP)
#define WS_PART_BYTE 54525952ull  // 52 MiB
#define WS_PART_END  (WS_PART_BYTE + 4ull*NCHUNK*512*256)
#define NEGBIG (-1.0e30f)

typedef short short8 __attribute__((ext_vector_type(8)));
typedef float f32x4  __attribute__((ext_vector_type(4)));

static __device__ __forceinline__ unsigned short f2bfu(float f) {
  union { __hip_bfloat16 h; unsigned short u; } cv;
  cv.h = __float2bfloat16(f);
  return cv.u;
}

static __device__ __forceinline__ short8 pack8(float4 a, float4 b) {
  short8 r;
  r[0] = (short)f2bfu(a.x); r[1] = (short)f2bfu(a.y);
  r[2] = (short)f2bfu(a.z); r[3] = (short)f2bfu(a.w);
  r[4] = (short)f2bfu(b.x); r[5] = (short)f2bfu(b.y);
  r[6] = (short)f2bfu(b.z); r[7] = (short)f2bfu(b.w);
  return r;
}

// ---------------- k0: x norms + zero retrieved ----------------
__global__ void k0_xn(const float* __restrict__ x, float* __restrict__ ws,
                      float* __restrict__ out) {
  const int b = blockIdx.x, t = threadIdx.x;
  const float v = x[b*DDIM + t];
  float s = v*v;
  #pragma unroll
  for (int mk = 1; mk <= 32; mk <<= 1) s += __shfl_xor(s, mk);
  __shared__ float ps[4];
  if ((t & 63) == 0) ps[t >> 6] = s;
  __syncthreads();
  if (t == 0) {
    const float tot = ps[0] + ps[1] + ps[2] + ps[3];
    ws[WS_RXN + b] = 10.0f / fmaxf(sqrtf(tot), 1e-12f);  // fold TEMP=10
  }
  out[b*DDIM + t] = 0.0f;
}

// ---------------- k0b: transpose V -> VT bf16 [256][MP] ----------------
__global__ __launch_bounds__(256) void k0b_tr(const float* __restrict__ V,
                                              float* __restrict__ ws) {
  const int t = threadIdx.x;
  const int m0 = blockIdx.x * 64;
  __shared__ float vt_f[64][261];  // pad 261: conflict-light column reads
  #pragma unroll
  for (int i = 0; i < 4; ++i) {
    const int ml = (t >> 4) + 16*i;
    const int mg = m0 + ml;
    #pragma unroll
    for (int j = 0; j < 4; ++j) {
      const int d = 4*(t & 15) + 64*j;
      float4 v = make_float4(0.f, 0.f, 0.f, 0.f);
      if (mg < MCOLS) v = *(const float4*)(V + (size_t)mg*DDIM + d);
      vt_f[ml][d] = v.x; vt_f[ml][d+1] = v.y; vt_f[ml][d+2] = v.z; vt_f[ml][d+3] = v.w;
    }
  }
  __syncthreads();
  unsigned short* vt = (unsigned short*)((char*)ws + WS_VT_BYTE);
  const int mq = 4*(t & 15);
  #pragma unroll
  for (int it = 0; it < 16; ++it) {
    const int d = (t >> 4) + 16*it;
    uint2 u;
    u.x = (unsigned)f2bfu(vt_f[mq+0][d]) | ((unsigned)f2bfu(vt_f[mq+1][d]) << 16);
    u.y = (unsigned)f2bfu(vt_f[mq+2][d]) | ((unsigned)f2bfu(vt_f[mq+3][d]) << 16);
    *(uint2*)(vt + (size_t)d*MP + m0 + mq) = u;   // coalesced along m
  }
}

// ---------------- shared helpers for k1/k3 (identical logits) ----------------
static __device__ __forceinline__ void load_xf(const float* __restrict__ x,
                                               int brow0, int q, int ln,
                                               short8 xf[2][8]) {
  #pragma unroll
  for (int as = 0; as < 2; ++as) {
    const int row = brow0 + 16*as + ln;
    #pragma unroll
    for (int kk = 0; kk < 8; ++kk) {
      const float* p = x + row*DDIM + 32*kk + 8*q;
      const float4 v0 = *(const float4*)p;
      const float4 v1 = *(const float4*)(p + 4);
      xf[as][kk] = pack8(v0, v1);
    }
  }
}

static __device__ __forceinline__ void stage_k(const float* __restrict__ K,
                                               int m0, int t,
                                               unsigned short klds[64][264],
                                               float* rkn_s) {
  #pragma unroll
  for (int i = 0; i < 2; ++i) {
    const int ml = (t >> 4) + 32*i;
    const int mg = m0 + ml;
    float ss = 0.f;
    #pragma unroll
    for (int j = 0; j < 4; ++j) {
      const int d = 4*(t & 15) + 64*j;
      float4 v = make_float4(0.f, 0.f, 0.f, 0.f);
      if (mg < MCOLS) v = *(const float4*)(K + (size_t)mg*DDIM + d);
      ss += v.x*v.x + v.y*v.y + v.z*v.z + v.w*v.w;
      ushort4 u;
      u.x = f2bfu(v.x); u.y = f2bfu(v.y); u.z = f2bfu(v.z); u.w = f2bfu(v.w);
      *(ushort4*)&klds[ml][d] = u;
    }
    ss += __shfl_xor(ss, 1); ss += __shfl_xor(ss, 2);
    ss += __shfl_xor(ss, 4); ss += __shfl_xor(ss, 8);
    if ((t & 15) == 0) rkn_s[ml] = 1.0f / fmaxf(sqrtf(ss), 1e-12f);
  }
}

static __device__ __forceinline__ void gemm64(const short8 xf[2][8],
                                              const unsigned short klds[64][264],
                                              int w, int q, int ln,
                                              f32x4 acc[2][2]) {
  const int msub = 32*(w & 1);
  #pragma unroll
  for (int kk = 0; kk < 8; ++kk) {
    const short8 b0 = *(const short8*)&klds[msub + ln][32*kk + 8*q];
    const short8 b1 = *(const short8*)&klds[msub + 16 + ln][32*kk + 8*q];
    #pragma unroll
    for (int as = 0; as < 2; ++as) {
      acc[as][0] = __builtin_amdgcn_mfma_f32_16x16x32_bf16(xf[as][kk], b0, acc[as][0], 0, 0, 0);
      acc[as][1] = __builtin_amdgcn_mfma_f32_16x16x32_bf16(xf[as][kk], b1, acc[as][1], 0, 0, 0);
    }
  }
}

// ---------------- k1: online softmax stats ----------------
__global__ __launch_bounds__(512) void k1_stats(const float* __restrict__ x,
                                                const float* __restrict__ K,
                                                const float* __restrict__ ws,
                                                float* __restrict__ out) {
  const int c = blockIdx.x, rb = blockIdx.y;
  const int t = threadIdx.x;
  const int w = t >> 6, l = t & 63, q = l >> 4, ln = l & 15;
  __shared__ __align__(16) unsigned short klds[64][264];
  __shared__ float rkn_s[64];

  short8 xf[2][8];
  const int brow0 = rb*128 + 32*(w >> 1);
  load_xf(x, brow0, q, ln, xf);

  float rxn[2][4];
  #pragma unroll
  for (int as = 0; as < 2; ++as)
    #pragma unroll
    for (int r = 0; r < 4; ++r)
      rxn[as][r] = ws[WS_RXN + brow0 + 16*as + 4*q + r];

  float mpr[2][4], lpr[2][4];
  #pragma unroll
  for (int as = 0; as < 2; ++as)
    #pragma unroll
    for (int r = 0; r < 4; ++r) { mpr[as][r] = NEGBIG; lpr[as][r] = 0.f; }

  const int mbase = c*CHUNK;
  const int mrem = MCOLS - mbase;
  const int nt = (mrem >= CHUNK) ? NTFULL : ((mrem + 63) >> 6);

  for (int mt = 0; mt < nt; ++mt) {
    const int m0 = mbase + mt*64;
    stage_k(K, m0, t, klds, rkn_s);
    __syncthreads();
    f32x4 acc[2][2];
    #pragma unroll
    for (int as = 0; as < 2; ++as)
      #pragma unroll
      for (int mm = 0; mm < 2; ++mm) { f32x4 z = {0.f,0.f,0.f,0.f}; acc[as][mm] = z; }
    gemm64(xf, klds, w, q, ln, acc);
    const int msub = 32*(w & 1);
    #pragma unroll
    for (int mm = 0; mm < 2; ++mm) {
      const int cl = msub + 16*mm + ln;
      const int cg = m0 + cl;
      const float rkn = rkn_s[cl];
      const bool ok = cg < MCOLS;
      #pragma unroll
      for (int as = 0; as < 2; ++as)
        #pragma unroll
        for (int r = 0; r < 4; ++r) {
          const float lg = ok ? acc[as][mm][r]*rxn[as][r]*rkn : NEGBIG;
          const float dd = lg - mpr[as][r];
          if (dd > 0.f) { lpr[as][r] = lpr[as][r]*__expf(-dd) + 1.f; mpr[as][r] = lg; }
          else          { lpr[as][r] += __expf(dd); }
        }
    }
    __syncthreads();
  }

  float* pst = out + PSTAT_OFF;
  #pragma unroll
  for (int as = 0; as < 2; ++as)
    #pragma unroll
    for (int r = 0; r < 4; ++r) {
      float m = mpr[as][r], lsv = lpr[as][r];
      #pragma unroll
      for (int mk = 1; mk <= 8; mk <<= 1) {
        const float om = __shfl_xor(m, mk);
        const float ol = __shfl_xor(lsv, mk);
        const float nm = fmaxf(m, om);
        lsv = lsv*__expf(m - nm) + ol*__expf(om - nm);
        m = nm;
      }
      if (ln == 0) {
        const int row = rb*128 + 32*(w >> 1) + 16*as + 4*q + r;
        const size_t e = (size_t)c*2 + (w & 1);   // per m-half entry (avoids wave race)
        pst[(e*512 + row)*2]     = m;
        pst[(e*512 + row)*2 + 1] = lsv;
      }
    }
}

// ---------------- k2: merge stats ----------------
__global__ void k2_final(const float* __restrict__ out, float* __restrict__ ws) {
  const int b = blockIdx.x, t = threadIdx.x;   // 512 blocks x 256 thr
  const float* pst = out + PSTAT_OFF;
  float mi = NEGBIG, lv = 0.f;
  if (t < NSTAT) {
    const float2 v = *(const float2*)(pst + ((size_t)t*512 + b)*2);
    mi = v.x; lv = v.y;
  }
  float m = mi;
  #pragma unroll
  for (int mk = 1; mk <= 32; mk <<= 1) m = fmaxf(m, __shfl_xor(m, mk));
  __shared__ float sm[4], sl[4];
  if ((t & 63) == 0) sm[t >> 6] = m;
  __syncthreads();
  m = fmaxf(fmaxf(sm[0], sm[1]), fmaxf(sm[2], sm[3]));
  float term = lv*__expf(mi - m);
  #pragma unroll
  for (int mk = 1; mk <= 32; mk <<= 1) term += __shfl_xor(term, mk);
  if ((t & 63) == 0) sl[t >> 6] = term;
  __syncthreads();
  if (t == 0) {
    const float lsum = sl[0] + sl[1] + sl[2] + sl[3];
    ws[WS_MFIN + b] = m;
    ws[WS_RCPL + b] = 1.0f / lsum;
  }
}

// ---------------- k3: attn write + PV accumulate ----------------
template<bool USEVT, bool USEPART>
__global__ __launch_bounds__(512) void k3_attn(const float* __restrict__ x,
                                               const float* __restrict__ K,
                                               const float* __restrict__ V,
                                               float* __restrict__ ws,
                                               float* __restrict__ out) {
  const int c = blockIdx.x, rb = blockIdx.y;
  const int t = threadIdx.x;
  const int w = t >> 6, l = t & 63, q = l >> 4, ln = l & 15;
  __shared__ __align__(16) unsigned short klds[64][264];   // K tile; reused as p-tile
  __shared__ __align__(16) unsigned short vtl[256][72];    // V^T tile
  __shared__ float rkn_s[64];
  unsigned short (*plds)[72] = reinterpret_cast<unsigned short(*)[72]>(&klds[0][0]);

  short8 xf[2][8];
  const int brow0 = rb*128 + 32*(w >> 1);
  load_xf(x, brow0, q, ln, xf);

  float rxn[2][4], mf[2][4], rl[2][4];
  #pragma unroll
  for (int as = 0; as < 2; ++as)
    #pragma unroll
    for (int r = 0; r < 4; ++r) {
      const int row = brow0 + 16*as + 4*q + r;
      rxn[as][r] = ws[WS_RXN  + row];
      mf[as][r]  = ws[WS_MFIN + row];
      rl[as][r]  = ws[WS_RCPL + row];
    }

  f32x4 apv[2][8];
  #pragma unroll
  for (int bs = 0; bs < 2; ++bs)
    #pragma unroll
    for (int dx = 0; dx < 8; ++dx) { f32x4 z = {0.f,0.f,0.f,0.f}; apv[bs][dx] = z; }

  float* attn = out + 131072;
  const int mbase = c*CHUNK;
  const int mrem = MCOLS - mbase;
  const int nt = (mrem >= CHUNK) ? NTFULL : ((mrem + 63) >> 6);

  for (int mt = 0; mt < nt; ++mt) {
    const int m0 = mbase + mt*64;
    stage_k(K, m0, t, klds, rkn_s);
    if (USEVT) {
      const unsigned short* vt = (const unsigned short*)((const char*)ws + WS_VT_BYTE);
      const int d = t >> 1;
      const unsigned short* vrow = vt + (size_t)d*MP + m0;
      #pragma unroll
      for (int k2 = 0; k2 < 4; ++k2) {
        const uint4 u = *(const uint4*)((const char*)vrow + (t & 1)*64 + 16*k2);
        *(uint4*)&vtl[d][(t & 1)*32 + 8*k2] = u;
      }
    } else {
      // fallback: transpose in LDS with scalar writes (slow, correct)
      #pragma unroll
      for (int i = 0; i < 2; ++i) {
        const int ml = (t >> 4) + 32*i;
        const int mg = m0 + ml;
        #pragma unroll
        for (int j = 0; j < 4; ++j) {
          const int d = 4*(t & 15) + 64*j;
          float4 v = make_float4(0.f, 0.f, 0.f, 0.f);
          if (mg < MCOLS) v = *(const float4*)(V + (size_t)mg*DDIM + d);
          vtl[d+0][ml] = f2bfu(v.x); vtl[d+1][ml] = f2bfu(v.y);
          vtl[d+2][ml] = f2bfu(v.z); vtl[d+3][ml] = f2bfu(v.w);
        }
      }
    }
    __syncthreads();
    f32x4 acc[2][2];
    #pragma unroll
    for (int as = 0; as < 2; ++as)
      #pragma unroll
      for (int mm = 0; mm < 2; ++mm) { f32x4 z = {0.f,0.f,0.f,0.f}; acc[as][mm] = z; }
    gemm64(xf, klds, w, q, ln, acc);
    __syncthreads();                 // all K reads done before p overwrites klds
    const int msub = 32*(w & 1);
    #pragma unroll
    for (int mm = 0; mm < 2; ++mm) {
      const int cl = msub + 16*mm + ln;
      const int cg = m0 + cl;
      const float rkn = rkn_s[cl];
      const bool ok = cg < MCOLS;
      #pragma unroll
      for (int as = 0; as < 2; ++as)
        #pragma unroll
        for (int r = 0; r < 4; ++r) {
          const int rowl = 32*(w >> 1) + 16*as + 4*q + r;
          const float lg = acc[as][mm][r]*rxn[as][r]*rkn;
          const float p = ok ? __expf(lg - mf[as][r]) : 0.f;
          if (ok) attn[(size_t)(rb*128 + rowl)*MCOLS + cg] = p*rl[as][r];
          plds[rowl][cl] = f2bfu(p);   // unnormalized p for PV
        }
    }
    __syncthreads();
    {
      const int b2 = 32*(w & 3), d2 = 128*(w >> 2);
      #pragma unroll
      for (int ks = 0; ks < 2; ++ks) {
        short8 af[2];
        #pragma unroll
        for (int bs = 0; bs < 2; ++bs)
          af[bs] = *(const short8*)&plds[b2 + 16*bs + ln][32*ks + 8*q];
        #pragma unroll
        for (int dx = 0; dx < 8; ++dx) {
          const short8 bv = *(const short8*)&vtl[d2 + 16*dx + ln][32*ks + 8*q];
          #pragma unroll
          for (int bs = 0; bs < 2; ++bs)
            apv[bs][dx] = __builtin_amdgcn_mfma_f32_16x16x32_bf16(af[bs], bv, apv[bs][dx], 0, 0, 0);
        }
      }
    }
    __syncthreads();                 // PV reads done before next staging
  }

  const int b2 = 32*(w & 3), d2 = 128*(w >> 2);
  float rlp[2][4];
  #pragma unroll
  for (int bs = 0; bs < 2; ++bs)
    #pragma unroll
    for (int r = 0; r < 4; ++r)
      rlp[bs][r] = ws[WS_RCPL + rb*128 + b2 + 16*bs + 4*q + r];
  #pragma unroll
  for (int bs = 0; bs < 2; ++bs)
    #pragma unroll
    for (int dx = 0; dx < 8; ++dx)
      #pragma unroll
      for (int r = 0; r < 4; ++r) {
        const int row = rb*128 + b2 + 16*bs + 4*q + r;
        const int dcol = d2 + 16*dx + ln;
        const float val = apv[bs][dx][r]*rlp[bs][r];
        if (USEPART) {
          float* part = (float*)((char*)ws + WS_PART_BYTE);
          part[((size_t)c*512 + row)*256 + dcol] = val;
        } else {
          atomicAdd(out + (size_t)row*256 + dcol, val);
        }
      }
}

// ---------------- k4: reduce retrieved partials ----------------
__global__ void k4_red(const float* __restrict__ ws, float* __restrict__ out) {
  const int b = blockIdx.x, t = threadIdx.x;
  const float* part = (const float*)((const char*)ws + WS_PART_BYTE);
  float acc = 0.f;
  for (int cc = 0; cc < NCHUNK; ++cc)
    acc += part[((size_t)cc*512 + b)*256 + t];
  out[b*DDIM + t] = acc;
}

extern "C" void kernel_launch(void* const* d_in, const int* in_sizes, int n_in,
                              void* d_out, int out_size, void* d_ws, size_t ws_size,
                              hipStream_t stream) {
  const float* x = (const float*)d_in[0];
  const float* K = (const float*)d_in[1];
  const float* V = (const float*)d_in[2];
  float* out = (float*)d_out;
  float* ws  = (float*)d_ws;
  const bool useVT   = ws_size >= WS_VT_END;
  const bool usePart = ws_size >= WS_PART_END;

  k0_xn<<<512, 256, 0, stream>>>(x, ws, out);
  if (useVT) k0b_tr<<<MP/64, 256, 0, stream>>>(V, ws);
  k1_stats<<<dim3(NCHUNK, 4), 512, 0, stream>>>(x, K, ws, out);
  k2_final<<<512, 256, 0, stream>>>(out, ws);
  const dim3 g3(NCHUNK, 4);
  if (useVT && usePart)      k3_attn<true,  true ><<<g3, 512, 0, stream>>>(x, K, V, ws, out);
  else if (useVT)            k3_attn<true,  false><<<g3, 512, 0, stream>>>(x, K, V, ws, out);
  else if (usePart)          k3_attn<false, true ><<<g3, 512, 0, stream>>>(x, K, V, ws, out);
  else                       k3_attn<false, false><<<g3, 512, 0, stream>>>(x, K, V, ws, out);
  if (usePart) k4_red<<<512, 256, 0, stream>>>(ws, out);
}